// Round 3
// baseline (20.923 us; speedup 1.0000x reference)
//
#include <hip/hip_runtime.h>

namespace {

constexpr int CH    = 256;   // channels
constexpr int HH    = 256;
constexpr int WW    = 256;
constexpr int NBOX  = 100;
constexpr int MAXN  = 100;

typedef float f4 __attribute__((ext_vector_type(4)));

// ---------------- kernel A: per-channel scalars S0..S3 -> ws ----------------
__global__ __launch_bounds__(128) void setup_kernel(
    const float* __restrict__ boxes,   // [100,8,3]
    const float* __restrict__ scores,  // [100]
    const float* __restrict__ feat,    // [256,256,256]
    float* __restrict__ S)             // ws: [256][4]
{
    __shared__ float sh_a[NBOX], sh_cx[NBOX], sh_cy[NBOX];
    __shared__ float sh_w00[NBOX], sh_w10[NBOX], sh_w01[NBOX], sh_w11[NBOX];
    __shared__ int   sh_t00[NBOX], sh_t10[NBOX], sh_t01[NBOX], sh_t11[NBOX];
    __shared__ int   sh_idx[MAXN];
    __shared__ int   sh_w0cnt;
    __shared__ float red[4];

    const int tid = threadIdx.x;
    const int c   = blockIdx.x;

    // compaction predicate (ascending-order nonzero, fill_value=0)
    bool p = false;
    if (tid < NBOX) p = scores[tid] > 0.0f;
    unsigned long long mask = __ballot(p);
    if (tid == 0) sh_w0cnt = (int)__popcll(mask);
    if (tid < MAXN) sh_idx[tid] = 0;

    if (tid < NBOX) {
        const float* bp = boxes + tid * 24;
        float lx = bp[0], ly = bp[1];
        float rx = lx,    ry = ly;
        #pragma unroll
        for (int k = 1; k < 8; ++k) {
            float x = bp[k * 3 + 0], y = bp[k * 3 + 1];
            lx = fminf(lx, x); rx = fmaxf(rx, x);
            ly = fminf(ly, y); ry = fmaxf(ry, y);
        }
        const float inv_vox = 1.0f / 160.0f;
        float cx = ((lx + rx) * 0.5f + 128.0f) * inv_vox;
        float cy = ((ly + ry) * 0.5f + 128.0f) * inv_vox;
        float lxn = (lx + 128.0f) * inv_vox, rxn = (rx + 128.0f) * inv_vox;
        float lyn = (ly + 128.0f) * inv_vox, ryn = (ry + 128.0f) * inv_vox;
        float bev = (ryn - lyn) * (rxn - lxn);
        sh_a[tid]  = 1.0f / (2.0f * bev * bev);
        sh_cx[tid] = cx;
        sh_cy[tid] = cy;

        // grid_sample taps (align_corners=False, zero padding)
        float ix = ((cx + 1.0f) * (float)WW - 1.0f) * 0.5f;
        float iy = ((cy + 1.0f) * (float)HH - 1.0f) * 0.5f;
        float x0f = floorf(ix), y0f = floorf(iy);
        float wx1 = ix - x0f, wx0 = 1.0f - wx1;
        float wy1 = iy - y0f, wy0 = 1.0f - wy1;
        int x0 = (int)x0f, y0 = (int)y0f;
        int x1 = x0 + 1,  y1 = y0 + 1;
        bool vx0 = (x0 >= 0) && (x0 < WW), vx1 = (x1 >= 0) && (x1 < WW);
        bool vy0 = (y0 >= 0) && (y0 < HH), vy1 = (y1 >= 0) && (y1 < HH);
        sh_w00[tid] = (vx0 && vy0) ? wx0 * wy0 : 0.0f;
        sh_w10[tid] = (vx1 && vy0) ? wx1 * wy0 : 0.0f;
        sh_w01[tid] = (vx0 && vy1) ? wx0 * wy1 : 0.0f;
        sh_w11[tid] = (vx1 && vy1) ? wx1 * wy1 : 0.0f;
        int cx0 = min(max(x0, 0), WW - 1), cx1 = min(max(x1, 0), WW - 1);
        int cy0 = min(max(y0, 0), HH - 1), cy1 = min(max(y1, 0), HH - 1);
        sh_t00[tid] = cy0 * WW + cx0;
        sh_t10[tid] = cy0 * WW + cx1;
        sh_t01[tid] = cy1 * WW + cx0;
        sh_t11[tid] = cy1 * WW + cx1;
    }
    __syncthreads();

    if (p) {
        int lane = tid & 63;
        int pos  = (tid >= 64 ? sh_w0cnt : 0)
                 + (int)__popcll(mask & ((1ull << lane) - 1ull));
        sh_idx[pos] = tid;
    }
    __syncthreads();

    float S0 = 0.0f, S1 = 0.0f, S2 = 0.0f, S3 = 0.0f;
    if (tid < MAXN) {
        const int j = sh_idx[tid];
        const float* fc = feat + (size_t)c * (HH * WW);
        float cpf = fc[sh_t00[j]] * sh_w00[j]
                  + fc[sh_t10[j]] * sh_w10[j]
                  + fc[sh_t01[j]] * sh_w01[j]
                  + fc[sh_t11[j]] * sh_w11[j];
        float pa = cpf * sh_a[j];
        float cx = sh_cx[j], cy = sh_cy[j];
        S0 = pa;
        S1 = pa * cx;
        S2 = pa * cy;
        S3 = pa * (cx * cx + cy * cy);
    }
    #pragma unroll
    for (int off = 32; off > 0; off >>= 1) {
        S0 += __shfl_down(S0, off);
        S1 += __shfl_down(S1, off);
        S2 += __shfl_down(S2, off);
        S3 += __shfl_down(S3, off);
    }
    if (tid == 64) { red[0] = S0; red[1] = S1; red[2] = S2; red[3] = S3; }
    __syncthreads();
    if (tid == 0) {
        const float invN = 1.0f / (float)MAXN;
        f4 v;
        v.x = (S0 + red[0]) * invN;
        v.y = (S1 + red[1]) * invN;
        v.z = (S2 + red[2]) * invN;
        v.w = (S3 + red[3]) * invN;
        *(f4*)(S + c * 4) = v;
    }
}

// ---------------- kernel B: pure streaming fill ----------------
// out[c,h,w] = s0*(w^2+h^2) - 2w*s1 - 2h*s2 + s3
constexpr int BLK_B   = 256;
constexpr int BPC     = 8;           // blocks per channel
constexpr int V_PER_C = (HH * WW) / 4;   // 16384 float4 per channel
constexpr int V_PER_B = V_PER_C / BPC;   // 2048 float4 per block

__global__ __launch_bounds__(BLK_B) void fill_kernel(
    const float* __restrict__ S,     // [256][4]
    float* __restrict__ out)
{
    const int bid = blockIdx.x;
    const int c   = bid >> 3;
    const int tid = threadIdx.x;

    const f4 s = *(const f4*)(S + c * 4);
    const float s0 = s.x, s1 = s.y, s2 = s.z, s3 = s.w;

    // per-thread column (invariant: 64 float4 per row, 256 thr = 4 rows/iter)
    const float wbase = (float)((tid & 63) << 2);
    f4 wq;
    {
        float w0 = wbase, w1 = wbase + 1.0f, w2 = wbase + 2.0f, w3 = wbase + 3.0f;
        wq.x = s0 * (w0 * w0) - 2.0f * w0 * s1;
        wq.y = s0 * (w1 * w1) - 2.0f * w1 * s1;
        wq.z = s0 * (w2 * w2) - 2.0f * w2 * s1;
        wq.w = s0 * (w3 * w3) - 2.0f * w3 * s1;
    }

    f4* oc = (f4*)(out + (size_t)c * (HH * WW));
    const int beg = (bid & 7) * V_PER_B;
    #pragma unroll
    for (int it = 0; it < V_PER_B / BLK_B; ++it) {
        int i = beg + it * BLK_B + tid;
        float hf = (float)(i >> 6);
        float hterm = s0 * (hf * hf) - 2.0f * hf * s2 + s3;
        f4 v;
        v.x = wq.x + hterm;
        v.y = wq.y + hterm;
        v.z = wq.z + hterm;
        v.w = wq.w + hterm;
        __builtin_nontemporal_store(v, &oc[i]);
    }
}

} // namespace

extern "C" void kernel_launch(void* const* d_in, const int* in_sizes, int n_in,
                              void* d_out, int out_size, void* d_ws, size_t ws_size,
                              hipStream_t stream) {
    const float* boxes  = (const float*)d_in[0];  // pred_box_infra [100,8,3]
    const float* scores = (const float*)d_in[1];  // pred_score_infra [100]
    const float* feat   = (const float*)d_in[2];  // infra_features [1,256,256,256]
    float* out = (float*)d_out;                   // [1,256,256,256] f32
    float* S   = (float*)d_ws;                    // [256][4] scratch

    setup_kernel<<<dim3(CH), dim3(128), 0, stream>>>(boxes, scores, feat, S);
    fill_kernel<<<dim3(CH * BPC), dim3(BLK_B), 0, stream>>>(S, out);
}

// Round 4
// 18.523 us; speedup vs baseline: 1.1295x; 1.1295x over previous
//
#include <hip/hip_runtime.h>

namespace {

constexpr int CH    = 256;
constexpr int HH    = 256;
constexpr int WW    = 256;
constexpr int NBOX  = 100;
constexpr int MAXN  = 100;
constexpr int BLOCK = 256;
constexpr int SPLIT = 4;                  // blocks per channel
constexpr int VPC   = HH * WW / 4;        // 16384 float4 per channel
constexpr int VPB   = VPC / SPLIT;        // 4096 float4 per block
constexpr int ITER  = VPB / BLOCK;        // 16 stores per thread

typedef float f4 __attribute__((ext_vector_type(4)));

__global__ __launch_bounds__(BLOCK) void comm_kernel(
    const float* __restrict__ boxes,   // [100,8,3]
    const float* __restrict__ scores,  // [100]
    const float* __restrict__ feat,    // [256,256,256]
    float* __restrict__ out)           // [256,256,256]
{
    __shared__ float red[BLOCK / 64][4];
    __shared__ float sS[4];

    const int tid  = threadIdx.x;
    const int c    = blockIdx.x >> 2;      // SPLIT = 4
    const int part = blockIdx.x & 3;

    // ---- per-box term, fully in registers (no compaction needed):
    // S_k = sum_i p_i*term_i + (100-cnt)*term_0
    int   pc = 0;
    float T0 = 0.f, T1 = 0.f, T2 = 0.f, T3 = 0.f;   // predicate-weighted
    float U0 = 0.f, U1 = 0.f, U2 = 0.f, U3 = 0.f;   // raw (kept by tid 0)
    if (tid < NBOX) {
        bool p = scores[tid] > 0.0f;
        pc = p ? 1 : 0;

        const float* bp = boxes + tid * 24;
        float lx = bp[0], ly = bp[1];
        float rx = lx,    ry = ly;
        #pragma unroll
        for (int k = 1; k < 8; ++k) {
            float x = bp[k * 3 + 0], y = bp[k * 3 + 1];
            lx = fminf(lx, x); rx = fmaxf(rx, x);
            ly = fminf(ly, y); ry = fmaxf(ry, y);
        }
        const float inv_vox = 1.0f / 160.0f;
        float cx = ((lx + rx) * 0.5f + 128.0f) * inv_vox;
        float cy = ((ly + ry) * 0.5f + 128.0f) * inv_vox;
        float lxn = (lx + 128.0f) * inv_vox, rxn = (rx + 128.0f) * inv_vox;
        float lyn = (ly + 128.0f) * inv_vox, ryn = (ry + 128.0f) * inv_vox;
        float bev = (ryn - lyn) * (rxn - lxn);
        float a   = 1.0f / (2.0f * bev * bev);

        // grid_sample (align_corners=False, zero padding)
        float ix = ((cx + 1.0f) * (float)WW - 1.0f) * 0.5f;
        float iy = ((cy + 1.0f) * (float)HH - 1.0f) * 0.5f;
        float x0f = floorf(ix), y0f = floorf(iy);
        float wx1 = ix - x0f, wx0 = 1.0f - wx1;
        float wy1 = iy - y0f, wy0 = 1.0f - wy1;
        int x0 = (int)x0f, y0 = (int)y0f;
        int x1 = x0 + 1,  y1 = y0 + 1;
        bool vx0 = (x0 >= 0) && (x0 < WW), vx1 = (x1 >= 0) && (x1 < WW);
        bool vy0 = (y0 >= 0) && (y0 < HH), vy1 = (y1 >= 0) && (y1 < HH);
        float w00 = (vx0 && vy0) ? wx0 * wy0 : 0.0f;
        float w10 = (vx1 && vy0) ? wx1 * wy0 : 0.0f;
        float w01 = (vx0 && vy1) ? wx0 * wy1 : 0.0f;
        float w11 = (vx1 && vy1) ? wx1 * wy1 : 0.0f;
        int cx0 = min(max(x0, 0), WW - 1), cx1 = min(max(x1, 0), WW - 1);
        int cy0 = min(max(y0, 0), HH - 1), cy1 = min(max(y1, 0), HH - 1);

        const float* fc = feat + (size_t)c * (HH * WW);
        float cpf = fc[cy0 * WW + cx0] * w00
                  + fc[cy0 * WW + cx1] * w10
                  + fc[cy1 * WW + cx0] * w01
                  + fc[cy1 * WW + cx1] * w11;

        float pa = cpf * a;
        U0 = pa;
        U1 = pa * cx;
        U2 = pa * cy;
        U3 = pa * (cx * cx + cy * cy);
        if (p) { T0 = U0; T1 = U1; T2 = U2; T3 = U3; }
    }
    const int cnt = __syncthreads_count(pc);   // barrier #1 + popcount

    // ---- register shuffle-reduce within each wave ----
    #pragma unroll
    for (int off = 32; off > 0; off >>= 1) {
        T0 += __shfl_down(T0, off);
        T1 += __shfl_down(T1, off);
        T2 += __shfl_down(T2, off);
        T3 += __shfl_down(T3, off);
    }
    if ((tid & 63) == 0) {
        int wv = tid >> 6;
        red[wv][0] = T0; red[wv][1] = T1; red[wv][2] = T2; red[wv][3] = T3;
    }
    __syncthreads();                           // barrier #2
    if (tid == 0) {
        float e = (float)(MAXN - cnt);
        float t0 = e * U0, t1 = e * U1, t2 = e * U2, t3 = e * U3;
        #pragma unroll
        for (int wv = 0; wv < BLOCK / 64; ++wv) {
            t0 += red[wv][0]; t1 += red[wv][1];
            t2 += red[wv][2]; t3 += red[wv][3];
        }
        const float invN = 1.0f / (float)MAXN;
        sS[0] = t0 * invN; sS[1] = t1 * invN;
        sS[2] = t2 * invN; sS[3] = t3 * invN;
    }
    __syncthreads();                           // barrier #3

    // ---- streaming fill: out = s0*(w^2+h^2) - 2w*s1 - 2h*s2 + s3 ----
    const float s0 = sS[0], s1 = sS[1], s2 = sS[2], s3 = sS[3];

    const float wbase = (float)((tid & 63) << 2);  // column invariant per thread
    f4 wq;
    {
        float w0 = wbase, w1 = wbase + 1.0f, w2 = wbase + 2.0f, w3 = wbase + 3.0f;
        wq.x = s0 * (w0 * w0) - 2.0f * w0 * s1;
        wq.y = s0 * (w1 * w1) - 2.0f * w1 * s1;
        wq.z = s0 * (w2 * w2) - 2.0f * w2 * s1;
        wq.w = s0 * (w3 * w3) - 2.0f * w3 * s1;
    }

    f4* oc = (f4*)(out + (size_t)c * (HH * WW));
    const int beg = part * VPB;
    #pragma unroll
    for (int it = 0; it < ITER; ++it) {
        int i = beg + it * BLOCK + tid;
        float hf = (float)(i >> 6);
        float hterm = s0 * (hf * hf) - 2.0f * hf * s2 + s3;
        f4 v;
        v.x = wq.x + hterm;
        v.y = wq.y + hterm;
        v.z = wq.z + hterm;
        v.w = wq.w + hterm;
        __builtin_nontemporal_store(v, &oc[i]);
    }
}

} // namespace

extern "C" void kernel_launch(void* const* d_in, const int* in_sizes, int n_in,
                              void* d_out, int out_size, void* d_ws, size_t ws_size,
                              hipStream_t stream) {
    const float* boxes  = (const float*)d_in[0];  // pred_box_infra [100,8,3]
    const float* scores = (const float*)d_in[1];  // pred_score_infra [100]
    const float* feat   = (const float*)d_in[2];  // infra_features [1,256,256,256]
    float* out = (float*)d_out;                   // [1,256,256,256] f32
    comm_kernel<<<dim3(CH * SPLIT), dim3(BLOCK), 0, stream>>>(boxes, scores, feat, out);
}